// Round 1
// baseline (292.815 us; speedup 1.0000x reference)
//
#include <hip/hip_runtime.h>

// MultiHeadAttention: BS=4, N=2048, D=512, H=8, DK=64. fp32 in/out, bf16 MFMA compute.
// Round 6: att_mas bit-packed (1 uint4/lane/tile instead of 32 scalar loads);
// QK^T operands swapped so P packs into ds_write_b64 (8 writes/tile, conflict-free);
// log2(e)/8 folded into Qh projection.

#define BS_    4
#define NSEQ   2048
#define DMODEL 512
#define NH     8
#define DKH    64
#define MROWS  (BS_ * NSEQ)   // 8192
#define NW32   (NSEQ / 32)    // 64 mask words per row

typedef unsigned short ushort_t;
typedef __attribute__((ext_vector_type(8))) short short8;   // 8 bf16 (4 VGPRs)
typedef __attribute__((ext_vector_type(4))) float floatx4;  // 4 fp32 acc

__device__ __forceinline__ ushort_t f2bf(float f) {
    unsigned int x = __builtin_bit_cast(unsigned int, f);
    unsigned int lsb = (x >> 16) & 1u;
    x += 0x7fffu + lsb;          // round-to-nearest-even
    return (ushort_t)(x >> 16);
}
__device__ __forceinline__ floatx4 mfma_bf16(short8 a, short8 b, floatx4 c) {
    return __builtin_amdgcn_mfma_f32_16x16x32_bf16(a, b, c, 0, 0, 0);
}
__device__ __forceinline__ void gld16(const ushort_t* g, ushort_t* l) {
    __builtin_amdgcn_global_load_lds(
        (const __attribute__((address_space(1))) unsigned int*)g,
        (__attribute__((address_space(3))) unsigned int*)l, 16, 0, 0);
}
__device__ __forceinline__ unsigned int cvt_pk_bf16(float lo, float hi) {
    unsigned int r;
    asm("v_cvt_pk_bf16_f32 %0, %1, %2" : "=v"(r) : "v"(lo), "v"(hi));
    return r;
}

// ---------------- fp32 -> bf16 converts ----------------
__global__ __launch_bounds__(256) void cvt3_kernel(const float* __restrict__ a,
                                                   const float* __restrict__ b,
                                                   const float* __restrict__ c,
                                                   ushort_t* __restrict__ dst, int n4) {
    const float* src = (blockIdx.y == 0) ? a : (blockIdx.y == 1) ? b : c;
    ushort_t* d = dst + (size_t)blockIdx.y * ((size_t)n4 * 4);
    const int i = blockIdx.x * blockDim.x + threadIdx.x;
    const float4 v = ((const float4*)src)[i];
    ushort4 o;
    o.x = f2bf(v.x); o.y = f2bf(v.y); o.z = f2bf(v.z); o.w = f2bf(v.w);
    ((ushort4*)d)[i] = o;
}

__global__ __launch_bounds__(256) void cvt4_kernel(const float* __restrict__ a,
                                                   const float* __restrict__ b,
                                                   const float* __restrict__ c,
                                                   const float* __restrict__ e,
                                                   ushort_t* __restrict__ dst, int n4) {
    const float* src = (blockIdx.y == 0) ? a : (blockIdx.y == 1) ? b
                     : (blockIdx.y == 2) ? c : e;
    ushort_t* d = dst + (size_t)blockIdx.y * ((size_t)n4 * 4);
    const int i = blockIdx.x * blockDim.x + threadIdx.x;
    const float4 v = ((const float4*)src)[i];
    ushort4 o;
    o.x = f2bf(v.x); o.y = f2bf(v.y); o.z = f2bf(v.z); o.w = f2bf(v.w);
    ((ushort4*)d)[i] = o;
}

// ---------------- att_mas -> bit pack (1 bit per element) ----------------
// word t covers att[32t .. 32t+31]; bit j = (att[32t+j] != 0)
__global__ __launch_bounds__(256) void mask_pack(const float* __restrict__ am,
                                                 unsigned int* __restrict__ mb) {
    const int t = blockIdx.x * 256 + threadIdx.x;
    const float4* src = (const float4*)am + (size_t)t * 8;
    unsigned int m = 0;
#pragma unroll
    for (int j = 0; j < 8; ++j) {
        const float4 v = src[j];
        m |= (v.x != 0.f ? 1u : 0u) << (4 * j);
        m |= (v.y != 0.f ? 1u : 0u) << (4 * j + 1);
        m |= (v.z != 0.f ? 1u : 0u) << (4 * j + 2);
        m |= (v.w != 0.f ? 1u : 0u) << (4 * j + 3);
    }
    mb[t] = m;
}

// ---------------- fused projection GEMM (Q/K/V via blockIdx.z) ----------------
__global__ __launch_bounds__(256) void gemm_proj(const ushort_t* __restrict__ Xall,
                                                 const ushort_t* __restrict__ Wall,
                                                 const float* __restrict__ qmas,
                                                 const float* __restrict__ kmas,
                                                 ushort_t* __restrict__ Qh,
                                                 ushort_t* __restrict__ Kh,
                                                 ushort_t* __restrict__ Vt) {
    __shared__ ushort_t As[128 * 32];
    __shared__ ushort_t Bs[128 * 32];
    const int z = blockIdx.z;
    const ushort_t* X  = Xall + (size_t)z * MROWS * DMODEL;
    const ushort_t* Wb = Wall + (size_t)z * DMODEL * DMODEL;
    const float* rowmask = (z == 0) ? qmas : kmas;

    const int tid  = threadIdx.x;
    const int wave = tid >> 6;
    const int lane = tid & 63;
    const int l16  = lane & 15;
    const int quad = lane >> 4;
    const int wr   = wave >> 1;
    const int wc   = wave & 1;
    const int m0   = blockIdx.x * 128;
    const int n0   = blockIdx.y * 128;
    const int crow = lane >> 2;
    const int koff = (lane & 3) * 8;

    floatx4 acc[4][4];
#pragma unroll
    for (int t = 0; t < 4; ++t)
#pragma unroll
        for (int u = 0; u < 4; ++u) acc[t][u] = (floatx4){0.f, 0.f, 0.f, 0.f};

    for (int k0 = 0; k0 < DMODEL; k0 += 32) {
#pragma unroll
        for (int c2 = 0; c2 < 2; ++c2) {
            const int c = wave * 2 + c2;
            gld16(X  + (size_t)(m0 + c * 16 + crow) * DMODEL + k0 + koff, &As[c * 512]);
            gld16(Wb + (size_t)(n0 + c * 16 + crow) * DMODEL + k0 + koff, &Bs[c * 512]);
        }
        __syncthreads();
        short8 a[4], b[4];
#pragma unroll
        for (int t = 0; t < 4; ++t)
            a[t] = *(const short8*)&As[(wr * 64 + t * 16 + l16) * 32 + quad * 8];
#pragma unroll
        for (int u = 0; u < 4; ++u)
            b[u] = *(const short8*)&Bs[(wc * 64 + u * 16 + l16) * 32 + quad * 8];
#pragma unroll
        for (int t = 0; t < 4; ++t)
#pragma unroll
            for (int u = 0; u < 4; ++u) acc[t][u] = mfma_bf16(a[t], b[u], acc[t][u]);
        __syncthreads();
    }

    float rm[4][4];
#pragma unroll
    for (int t = 0; t < 4; ++t)
#pragma unroll
        for (int r = 0; r < 4; ++r)
            rm[t][r] = rowmask[m0 + wr * 64 + t * 16 + quad * 4 + r];
    if (z == 0) {
        // fold log2(e)/sqrt(dk) into Qh so attn uses exp2(S) directly
#pragma unroll
        for (int t = 0; t < 4; ++t)
#pragma unroll
            for (int r = 0; r < 4; ++r) rm[t][r] *= 0.18033688011112042f;
    }

    const int bb    = m0 >> 11;
    const int nbase = (m0 & (NSEQ - 1)) + wr * 64;
#pragma unroll
    for (int t = 0; t < 4; ++t) {
#pragma unroll
        for (int u = 0; u < 4; ++u) {
            const int d = n0 + wc * 64 + u * 16 + l16;
            const int h = d >> 6, cc = d & 63;
            if (z < 2) {
                ushort_t* dst = (z == 0) ? Qh : Kh;
#pragma unroll
                for (int r = 0; r < 4; ++r) {
                    const int n = nbase + t * 16 + quad * 4 + r;
                    dst[((size_t)(bb * NH + h) * NSEQ + n) * DKH + cc] =
                        f2bf(acc[t][u][r] * rm[t][r]);
                }
            } else {
                ushort4 pk;
                pk.x = f2bf(acc[t][u][0] * rm[t][0]);
                pk.y = f2bf(acc[t][u][1] * rm[t][1]);
                pk.z = f2bf(acc[t][u][2] * rm[t][2]);
                pk.w = f2bf(acc[t][u][3] * rm[t][3]);
                const int n = nbase + t * 16 + quad * 4;
                *(ushort4*)(Vt + ((size_t)(bb * NH + h) * DKH + cc) * NSEQ + n) = pk;
            }
        }
    }
}

// ---------------- output GEMM ----------------
__global__ __launch_bounds__(256) void gemm_out(const ushort_t* __restrict__ X,
                                                const ushort_t* __restrict__ Wb,
                                                const float* __restrict__ rowmask,
                                                float* __restrict__ dst) {
    __shared__ ushort_t As[128 * 32];
    __shared__ ushort_t Bs[128 * 32];
    const int tid  = threadIdx.x;
    const int wave = tid >> 6;
    const int lane = tid & 63;
    const int l16  = lane & 15;
    const int quad = lane >> 4;
    const int wr   = wave >> 1;
    const int wc   = wave & 1;
    const int m0   = blockIdx.x * 128;
    const int n0   = blockIdx.y * 128;
    const int crow = lane >> 2;
    const int koff = (lane & 3) * 8;

    floatx4 acc[4][4];
#pragma unroll
    for (int t = 0; t < 4; ++t)
#pragma unroll
        for (int u = 0; u < 4; ++u) acc[t][u] = (floatx4){0.f, 0.f, 0.f, 0.f};

    for (int k0 = 0; k0 < DMODEL; k0 += 32) {
#pragma unroll
        for (int c2 = 0; c2 < 2; ++c2) {
            const int c = wave * 2 + c2;
            gld16(X  + (size_t)(m0 + c * 16 + crow) * DMODEL + k0 + koff, &As[c * 512]);
            gld16(Wb + (size_t)(n0 + c * 16 + crow) * DMODEL + k0 + koff, &Bs[c * 512]);
        }
        __syncthreads();
        short8 a[4], b[4];
#pragma unroll
        for (int t = 0; t < 4; ++t)
            a[t] = *(const short8*)&As[(wr * 64 + t * 16 + l16) * 32 + quad * 8];
#pragma unroll
        for (int u = 0; u < 4; ++u)
            b[u] = *(const short8*)&Bs[(wc * 64 + u * 16 + l16) * 32 + quad * 8];
#pragma unroll
        for (int t = 0; t < 4; ++t)
#pragma unroll
            for (int u = 0; u < 4; ++u) acc[t][u] = mfma_bf16(a[t], b[u], acc[t][u]);
        __syncthreads();
    }

#pragma unroll
    for (int t = 0; t < 4; ++t) {
#pragma unroll
        for (int r = 0; r < 4; ++r) {
            const int m = m0 + wr * 64 + t * 16 + quad * 4 + r;
            const float rm = rowmask[m];
#pragma unroll
            for (int u = 0; u < 4; ++u) {
                const int d = n0 + wc * 64 + u * 16 + l16;
                dst[(size_t)m * DMODEL + d] = acc[t][u][r] * rm;
            }
        }
    }
}

// ---------------- flash attention: 64-q blocks, LDS-staged 128-key tiles ----------------
// Qh (pre-scaled by log2e/8), Kh: [b][h][n][64] bf16;  Vt: [b][h][c][n] bf16;
// Mb: bit-packed att_mas; kmas fp32; y bf16.
// S computed TRANSPOSED (mfma(K,Q)): lane (l16,quad) reg r holds
// S[key = fr*16+quad*4+r][q = l16] -> 4 consecutive keys per lane -> P packs
// into one ds_write_b64 per fragment (conflict-free, 8 stores/tile vs 32).
__global__ __launch_bounds__(256) void attn_kernel(const ushort_t* __restrict__ Qh,
                                                   const ushort_t* __restrict__ Kh,
                                                   const ushort_t* __restrict__ Vt,
                                                   const unsigned int* __restrict__ Mb,
                                                   const float* __restrict__ kmas,
                                                   ushort_t* __restrict__ y) {
    __shared__ __align__(16) ushort_t Ks[128 * 72];      // 18432 B
    __shared__ __align__(16) ushort_t Vs[64 * 136];      // 17408 B
    __shared__ __align__(16) ushort_t Ps[4][16 * 136];   // 17408 B

    const int tid  = threadIdx.x;
    const int wave = tid >> 6;
    const int lane = tid & 63;
    const int l16  = lane & 15;
    const int quad = lane >> 4;
    const int h    = blockIdx.y;
    const int b    = blockIdx.z;
    const int qw   = blockIdx.x * 64 + wave * 16;   // this wave's 16 q-rows

    const ushort_t* Kb = Kh + (size_t)(b * NH + h) * NSEQ * DKH;
    const ushort_t* Vb = Vt + (size_t)(b * NH + h) * DKH * NSEQ;
    // per-lane mask row: q = qw + l16 (S^T layout puts one q-row per lane)
    const unsigned int* Mrow = Mb + ((size_t)(b * NSEQ + qw) + l16) * NW32;

    const ushort_t* Qp = Qh + ((size_t)((b * NH + h) * NSEQ) + qw + l16) * DKH + quad * 8;
    const short8 qfa = *(const short8*)Qp;
    const short8 qfb = *(const short8*)(Qp + 32);

    float lpart = 0.f;      // sum of P over this lane's 32 keys of row q=qw+l16
    floatx4 accO[4];
#pragma unroll
    for (int ct = 0; ct < 4; ++ct) accO[ct] = (floatx4){0.f, 0.f, 0.f, 0.f};

    for (int kt = 0; kt < NSEQ / 128; ++kt) {
        const int k0 = kt * 128;

        // ---- gather staging data into VGPRs (coalesced 16B/lane) ----
        short8 kv[4], vv[4];
#pragma unroll
        for (int i = 0; i < 4; ++i) {
            const int c = tid + i * 256;
            kv[i] = *(const short8*)(Kb + (size_t)(k0 + (c >> 3)) * DKH + (c & 7) * 8);
        }
#pragma unroll
        for (int i = 0; i < 4; ++i) {
            const int c = tid + i * 256;
            vv[i] = *(const short8*)(Vb + (size_t)(c >> 4) * NSEQ + k0 + (c & 15) * 8);
        }
        // ---- packed mask words for this lane's q-row, keys k0..k0+127 ----
        const uint4 mw = *(const uint4*)(Mrow + (k0 >> 5));

        __syncthreads();   // previous tile's LDS reads complete
#pragma unroll
        for (int i = 0; i < 4; ++i) {
            const int c = tid + i * 256;
            *(short8*)&Ks[(c >> 3) * 72 + (c & 7) * 8] = kv[i];
        }
#pragma unroll
        for (int i = 0; i < 4; ++i) {
            const int c = tid + i * 256;
            *(short8*)&Vs[(c >> 4) * 136 + (c & 15) * 8] = vv[i];
        }
        __syncthreads();   // tile staged

        // ---- S^T = K.Q^T for 128 keys x 16 q ----
        floatx4 S[8];
#pragma unroll
        for (int fr = 0; fr < 8; ++fr) {
            const short8 ka = *(const short8*)&Ks[(fr * 16 + l16) * 72 + quad * 8];
            const short8 kb = *(const short8*)&Ks[(fr * 16 + l16) * 72 + 32 + quad * 8];
            floatx4 s = {0.f, 0.f, 0.f, 0.f};
            s = mfma_bf16(ka, qfa, s);
            s = mfma_bf16(kb, qfb, s);
            S[fr] = s;
        }

        // ---- masked no-max softmax numerator; packed P -> wave-private LDS ----
        // pre-shift mask words so bit for (fr,r) is at compile-time position
        const unsigned int wsh[4] = {mw.x >> (quad * 4), mw.y >> (quad * 4),
                                     mw.z >> (quad * 4), mw.w >> (quad * 4)};
#pragma unroll
        for (int fr = 0; fr < 8; ++fr) {
            float p[4];
#pragma unroll
            for (int r = 0; r < 4; ++r) {
                const int bitp = ((fr & 1) << 4) + r;
                const unsigned int mm =
                    (unsigned int)((int)(wsh[fr >> 1] << (31 - bitp)) >> 31);
                const float e = exp2f(S[fr][r]);
                const unsigned int pb = __builtin_bit_cast(unsigned int, e) & mm;
                p[r] = __builtin_bit_cast(float, pb);
                lpart += p[r];
            }
            uint2 pk;
            pk.x = cvt_pk_bf16(p[0], p[1]);
            pk.y = cvt_pk_bf16(p[2], p[3]);
            *(uint2*)&Ps[wave][l16 * 136 + fr * 16 + quad * 4] = pk;
        }

        __builtin_amdgcn_wave_barrier();  // LDS W->R order (wave-local, in-order DS pipe)
        short8 pf[4];
#pragma unroll
        for (int kf = 0; kf < 4; ++kf)
            pf[kf] = *(const short8*)&Ps[wave][l16 * 136 + kf * 32 + quad * 8];
        __builtin_amdgcn_wave_barrier();

        // ---- O += P.V ----
#pragma unroll
        for (int ct = 0; ct < 4; ++ct) {
#pragma unroll
            for (int kf = 0; kf < 4; ++kf) {
                const short8 vb = *(const short8*)&Vs[(ct * 16 + l16) * 136 + kf * 32 + quad * 8];
                accO[ct] = mfma_bf16(pf[kf], vb, accO[ct]);
            }
        }
    }

    // ---- epilogue: reduce l across quads, normalize, post-mask, store ----
    float lfull = lpart;
    lfull += __shfl_xor(lfull, 16);
    lfull += __shfl_xor(lfull, 32);   // lane holds full l for q-row (qw + l16)
#pragma unroll
    for (int r = 0; r < 4; ++r) {
        const int q = qw + quad * 4 + r;
        const float l = __shfl(lfull, quad * 4 + r);  // l of row (qw + quad*4 + r)
        const float scale = kmas[b * NSEQ + q] / l;
#pragma unroll
        for (int ct = 0; ct < 4; ++ct) {
            y[(size_t)(b * NSEQ + q) * DMODEL + h * DKH + ct * 16 + l16] =
                f2bf(accO[ct][r] * scale);
        }
    }
}

extern "C" void kernel_launch(void* const* d_in, const int* in_sizes, int n_in,
                              void* d_out, int out_size, void* d_ws, size_t ws_size,
                              hipStream_t stream) {
    (void)in_sizes; (void)n_in; (void)out_size; (void)ws_size;
    const float* Q  = (const float*)d_in[0];
    const float* K  = (const float*)d_in[1];
    const float* V  = (const float*)d_in[2];
    const float* qm = (const float*)d_in[3];
    const float* km = (const float*)d_in[4];
    const float* am = (const float*)d_in[5];
    const float* WQ = (const float*)d_in[6];
    const float* WK = (const float*)d_in[7];
    const float* WV = (const float*)d_in[8];
    const float* WO = (const float*)d_in[9];

    const size_t XN = (size_t)MROWS * DMODEL;        // 4,194,304
    const size_t WN = (size_t)DMODEL * DMODEL;       // 262,144
    ushort_t* Xbf = (ushort_t*)d_ws;                 // Q,K,V bf16: 3*XN
    ushort_t* Wbf = Xbf + 3 * XN;                    // WQ,WK,WV,WO bf16: 4*WN
    ushort_t* WOb = Wbf + 3 * WN;
    ushort_t* Qh  = Wbf + 4 * WN;
    ushort_t* Kh  = Qh + XN;
    ushort_t* Vt  = Kh + XN;
    ushort_t* y   = Vt + XN;
    // packed mask aliases Xbf (dead after gemm_proj; mask_pack launches after it)
    unsigned int* Mbits = (unsigned int*)Xbf;
    float* out = (float*)d_out;

    hipLaunchKernelGGL(cvt3_kernel, dim3(4096, 3), dim3(256), 0, stream,
                       Q, K, V, Xbf, (int)(XN / 4));
    hipLaunchKernelGGL(cvt4_kernel, dim3(256, 4), dim3(256), 0, stream,
                       WQ, WK, WV, WO, Wbf, (int)(WN / 4));

    hipLaunchKernelGGL(gemm_proj, dim3(MROWS / 128, DMODEL / 128, 3), dim3(256), 0, stream,
                       Xbf, Wbf, qm, km, Qh, Kh, Vt);

    hipLaunchKernelGGL(mask_pack, dim3((BS_ * NSEQ * NSEQ / 32) / 256), dim3(256), 0, stream,
                       am, Mbits);

    hipLaunchKernelGGL(attn_kernel, dim3(NSEQ / 64, NH, BS_), dim3(256), 0, stream,
                       Qh, Kh, Vt, Mbits, km, y);

    hipLaunchKernelGGL(gemm_out, dim3(MROWS / 128, DMODEL / 128), dim3(256), 0, stream,
                       y, WOb, km, out);
}